// Round 13
// baseline (128.382 us; speedup 1.0000x reference)
//
#include <hip/hip_runtime.h>
#include <hip/hip_bf16.h>

#define D_EMB 1024
#define T_LEN 4096
#define NTASK2 544  // attn supertile-tasks per batch: sum of ceil((st+1)/4), st=0..63

typedef short short8 __attribute__((ext_vector_type(8)));
typedef float f32x4 __attribute__((ext_vector_type(4)));
typedef float f32x16 __attribute__((ext_vector_type(16)));
typedef float float4v __attribute__((ext_vector_type(4)));

__device__ __forceinline__ unsigned short f32_to_bf16(float f) {
    union { float f; unsigned int u; } c; c.f = f;
    unsigned int u = c.u;
    return (unsigned short)((u + 0x7FFFu + ((u >> 16) & 1u)) >> 16);
}
__device__ __forceinline__ float bf16_to_f32(unsigned short v) {
    union { unsigned int u; float f; } c; c.u = ((unsigned int)v) << 16;
    return c.f;
}
__device__ __forceinline__ unsigned cvtpk_bf16(float a, float b) {
    unsigned r;
    asm("v_cvt_pk_bf16_f32 %0, %1, %2" : "=v"(r) : "v"(a), "v"(b));
    return r;
}
// cross-half (lane i <-> i+32) reduce -- known-good __shfl_xor form
__device__ __forceinline__ float xhalf_max(float x) {
    return fmaxf(x, __shfl_xor(x, 32));
}
__device__ __forceinline__ float xhalf_add(float x) {
    return x + __shfl_xor(x, 32);
}

// scale folded into Q: 1/sqrt(64) * log2(e)  (softmax done in exp2 domain)
#define QSCALE (0.125f * 1.44269504f)

// ---------------- kernel 0: convert W (3 x 64x1024 fp32) -> bf16 Wb[192][1024], plain layout
__global__ __launch_bounds__(256) void convert_w(const float* __restrict__ Wk,
                                                 const float* __restrict__ Wq,
                                                 const float* __restrict__ Wv,
                                                 unsigned short* __restrict__ Wb) {
    int e = (blockIdx.x * 256 + threadIdx.x) * 8;
    const float* src;
    if (e < 65536) src = Wk + e;
    else if (e < 131072) src = Wq + (e - 65536);
    else src = Wv + (e - 131072);
    float4v a0 = *(const float4v*)src;
    float4v a1 = *(const float4v*)(src + 4);
    short8 r;
    r[0] = (short)f32_to_bf16(a0[0]); r[1] = (short)f32_to_bf16(a0[1]);
    r[2] = (short)f32_to_bf16(a0[2]); r[3] = (short)f32_to_bf16(a0[3]);
    r[4] = (short)f32_to_bf16(a1[0]); r[5] = (short)f32_to_bf16(a1[1]);
    r[6] = (short)f32_to_bf16(a1[2]); r[7] = (short)f32_to_bf16(a1[3]);
    *(short8*)(Wb + e) = r;
}

// ---------------- kernel 1: QKV projection, barrier-free, W direct from L2.
// Grid 1024 (BM=16 rows), 4 waves/block; wave w owns output cols [48w, 48w+48).
// __launch_bounds__(256, 4) -> 128 VGPR budget so the compiler can software-
// pipeline the unrolled loop's 5 independent loads/iter (R12's (256,8) capped
// VGPR at 64 -> VGPR_Count=24 -> zero loads in flight -> 2x regression).
__global__ __launch_bounds__(256, 4) void qkv_proj(const float* __restrict__ x,
                                                   const unsigned short* __restrict__ Wb,
                                                   unsigned short* __restrict__ Kb,
                                                   unsigned short* __restrict__ Qb,
                                                   unsigned short* __restrict__ Vt) {
    int tid = threadIdx.x;
    int lane = tid & 63, wave = tid >> 6;
    int lo = lane & 15, hi = lane >> 4;
    int row0 = blockIdx.x * 16;

    const float* xp = x + (size_t)(row0 + lo) * D_EMB + hi * 8;
    const unsigned short* wp = Wb + (size_t)(wave * 48 + lo) * D_EMB + hi * 8;

    f32x4 acc0 = (f32x4){0.f, 0.f, 0.f, 0.f};
    f32x4 acc1 = (f32x4){0.f, 0.f, 0.f, 0.f};
    f32x4 acc2 = (f32x4){0.f, 0.f, 0.f, 0.f};

#pragma unroll 8
    for (int kt = 0; kt < 32; kt++) {
        float4v a0 = *(const float4v*)(xp + kt * 32);
        float4v a1 = *(const float4v*)(xp + kt * 32 + 4);
        short8 b0 = *(const short8*)(wp + kt * 32);
        short8 b1 = *(const short8*)(wp + 16 * D_EMB + kt * 32);
        short8 b2 = *(const short8*)(wp + 32 * D_EMB + kt * 32);
        union { unsigned u[4]; short8 s; } c;
        c.u[0] = cvtpk_bf16(a0[0], a0[1]);
        c.u[1] = cvtpk_bf16(a0[2], a0[3]);
        c.u[2] = cvtpk_bf16(a1[0], a1[1]);
        c.u[3] = cvtpk_bf16(a1[2], a1[3]);
        acc0 = __builtin_amdgcn_mfma_f32_16x16x32_bf16(c.s, b0, acc0, 0, 0, 0);
        acc1 = __builtin_amdgcn_mfma_f32_16x16x32_bf16(c.s, b1, acc1, 0, 0, 0);
        acc2 = __builtin_amdgcn_mfma_f32_16x16x32_bf16(c.s, b2, acc2, 0, 0, 0);
    }

    // epilogue: acc i -> output col unit n = wave*3 + i (0..3 K, 4..7 Q, 8..11 V)
    f32x4 accs[3] = {acc0, acc1, acc2};
#pragma unroll
    for (int i = 0; i < 3; i++) {
        int n = wave * 3 + i;
#pragma unroll
        for (int r = 0; r < 4; r++) {
            int grow = row0 + hi * 4 + r;
            float val = accs[i][r];
            if (n < 4) {
                Kb[(size_t)grow * 64 + n * 16 + lo] = f32_to_bf16(val);
            } else if (n < 8) {
                Qb[(size_t)grow * 64 + (n - 4) * 16 + lo] = f32_to_bf16(val * QSCALE);
            } else {
                int bb = grow >> 12;
                Vt[((size_t)bb * 64 + (n - 8) * 16 + lo) * T_LEN + (grow & 4095)] = f32_to_bf16(val);
            }
        }
    }
}

// ---------------- kernel 2: causal flash attention, 1 wave per supertile-task.
// Wave handles TWO adjacent 32-row q-tiles (64-row supertile) against a shared
// chunk of <=8 32-key units: two independent softmax chains interleave in the
// SIMD (intra-wave ILP), K/V loads amortize 2x. Cross-half reduce via
// __shfl_xor (known-good). Branchless diagonal handling (mask -> exp2 -> 0).
__global__ __launch_bounds__(64, 2) void attn(const unsigned short* __restrict__ Qb,
                                              const unsigned short* __restrict__ Kb,
                                              const unsigned short* __restrict__ Vt,
                                              unsigned short* __restrict__ Opart,
                                              float* __restrict__ Mpart,
                                              float* __restrict__ Lpart) {
    int lane = threadIdx.x;
    int q32 = lane & 31;
    int hi = lane >> 5;
    unsigned lin = blockIdx.x;
    int b = lin & 3;
    int s = (int)(((lin >> 3) << 1) | ((lin >> 2) & 1));  // 0..543, heavy first

    // decode (supertile st, chunk c): group k has 4 supertiles, k chunks each
    int k = 16, rem = s;
    while (rem >= 4 * k) { rem -= 4 * k; k--; }
    int ti = rem / k;
    int st = 4 * k - 1 - ti;
    int c = rem - ti * k;

    int u0 = c * 8;
    int u1 = min(u0 + 8, 2 * st + 2);   // 32-key units
    int ta = 2 * st, tb = ta + 1;       // the two 32-row tiles
    int qrowA = 64 * st + q32;
    int qrowB = qrowA + 32;

    size_t base = (size_t)b * T_LEN;

    // Q B-fragments for both tiles
    short8 qfa[4], qfb[4];
    const unsigned short* qpa = Qb + (base + qrowA) * 64 + hi * 8;
    const unsigned short* qpb = Qb + (base + qrowB) * 64 + hi * 8;
#pragma unroll
    for (int d = 0; d < 4; d++) {
        qfa[d] = *(const short8*)(qpa + d * 16);
        qfb[d] = *(const short8*)(qpb + d * 16);
    }

    size_t vbase = ((size_t)b * 64 + q32) * T_LEN;
    f32x16 oA0 = {0.f}, oA1 = {0.f}, oB0 = {0.f}, oB1 = {0.f};
    float mA = -3e38f, lA = 0.f, mB = -3e38f, lB = 0.f;

    for (int u = u0; u < u1; ++u) {
        const unsigned short* kp = Kb + (base + u * 32 + q32) * 64 + hi * 8;
        short8 kc0 = *(const short8*)kp;
        short8 kc1 = *(const short8*)(kp + 16);
        short8 kc2 = *(const short8*)(kp + 32);
        short8 kc3 = *(const short8*)(kp + 48);
        const unsigned short* vp = Vt + vbase + u * 32 + hi * 8;
        short8 vc0 = *(const short8*)vp;
        short8 vc1 = *(const short8*)(vp + 16);
        short8 vc2 = *(const short8*)(vp + 32 * T_LEN);
        short8 vc3 = *(const short8*)(vp + 32 * T_LEN + 16);

        // S^T = K * Q^T for both tiles (independent MFMA chains)
        f32x16 sa = {0.f}, sb = {0.f};
        sa = __builtin_amdgcn_mfma_f32_32x32x16_bf16(kc0, qfa[0], sa, 0, 0, 0);
        sb = __builtin_amdgcn_mfma_f32_32x32x16_bf16(kc0, qfb[0], sb, 0, 0, 0);
        sa = __builtin_amdgcn_mfma_f32_32x32x16_bf16(kc1, qfa[1], sa, 0, 0, 0);
        sb = __builtin_amdgcn_mfma_f32_32x32x16_bf16(kc1, qfb[1], sb, 0, 0, 0);
        sa = __builtin_amdgcn_mfma_f32_32x32x16_bf16(kc2, qfa[2], sa, 0, 0, 0);
        sb = __builtin_amdgcn_mfma_f32_32x32x16_bf16(kc2, qfb[2], sb, 0, 0, 0);
        sa = __builtin_amdgcn_mfma_f32_32x32x16_bf16(kc3, qfa[3], sa, 0, 0, 0);
        sb = __builtin_amdgcn_mfma_f32_32x32x16_bf16(kc3, qfb[3], sb, 0, 0, 0);

        // causal mask: chain A when u >= ta (u==tb -> fully masked, harmless);
        // chain B only at u == tb
        if (u >= ta) {
#pragma unroll
            for (int r = 0; r < 16; ++r) {
                int key = 32 * u + (r & 3) + 8 * (r >> 2) + 4 * hi;
                sa[r] = (key <= qrowA) ? sa[r] : -3e38f;
                if (u == tb) sb[r] = (key <= qrowB) ? sb[r] : -3e38f;
            }
        }

        // row max (both chains) + cross-half
        float a0 = fmaxf(fmaxf(sa[0], sa[1]), sa[2]);
        float a1 = fmaxf(fmaxf(sa[3], sa[4]), sa[5]);
        float a2 = fmaxf(fmaxf(sa[6], sa[7]), sa[8]);
        float a3 = fmaxf(fmaxf(sa[9], sa[10]), sa[11]);
        float a4 = fmaxf(fmaxf(sa[12], sa[13]), sa[14]);
        float mxA = fmaxf(fmaxf(fmaxf(a0, a1), fmaxf(a2, a3)), fmaxf(a4, sa[15]));
        float b0 = fmaxf(fmaxf(sb[0], sb[1]), sb[2]);
        float b1 = fmaxf(fmaxf(sb[3], sb[4]), sb[5]);
        float b2 = fmaxf(fmaxf(sb[6], sb[7]), sb[8]);
        float b3 = fmaxf(fmaxf(sb[9], sb[10]), sb[11]);
        float b4 = fmaxf(fmaxf(sb[12], sb[13]), sb[14]);
        float mxB = fmaxf(fmaxf(fmaxf(b0, b1), fmaxf(b2, b3)), fmaxf(b4, sb[15]));
        mxA = xhalf_max(mxA);
        mxB = xhalf_max(mxB);

        // combined defer-max (THR=8): neutral rescale is exact for the
        // chain that didn't grow (al = exp2(0) = 1)
        float grow = fmaxf(mxA - mA, mxB - mB);
        if (__any(grow > 8.0f)) {
            float mnA = fmaxf(mA, mxA);
            float alA = exp2f(mA - mnA);
            mA = mnA; lA *= alA;
            float mnB = fmaxf(mB, mxB);
            float alB = exp2f(mB - mnB);
            mB = mnB; lB *= alB;
#pragma unroll
            for (int r = 0; r < 16; ++r) {
                oA0[r] *= alA; oA1[r] *= alA;
                oB0[r] *= alB; oB1[r] *= alB;
            }
        }

#pragma unroll
        for (int r = 0; r < 16; ++r) {
            sa[r] = exp2f(sa[r] - mA);
            sb[r] = exp2f(sb[r] - mB);
        }
        float yA = ((sa[0] + sa[8]) + (sa[4] + sa[12])) + ((sa[1] + sa[9]) + (sa[5] + sa[13]))
                 + ((sa[2] + sa[10]) + (sa[6] + sa[14])) + ((sa[3] + sa[11]) + (sa[7] + sa[15]));
        float yB = ((sb[0] + sb[8]) + (sb[4] + sb[12])) + ((sb[1] + sb[9]) + (sb[5] + sb[13]))
                 + ((sb[2] + sb[10]) + (sb[6] + sb[14])) + ((sb[3] + sb[11]) + (sb[7] + sb[15]));
        lA += xhalf_add(yA);
        lB += xhalf_add(yB);

        // pack P -> bf16 PV B-fragments (cvt_pk + permlane32_swap), both chains
        unsigned pa0 = cvtpk_bf16(sa[0],  sa[1]);
        unsigned pa1 = cvtpk_bf16(sa[2],  sa[3]);
        unsigned pa2 = cvtpk_bf16(sa[4],  sa[5]);
        unsigned pa3 = cvtpk_bf16(sa[6],  sa[7]);
        unsigned pa4 = cvtpk_bf16(sa[8],  sa[9]);
        unsigned pa5 = cvtpk_bf16(sa[10], sa[11]);
        unsigned pa6 = cvtpk_bf16(sa[12], sa[13]);
        unsigned pa7 = cvtpk_bf16(sa[14], sa[15]);
        unsigned pb0 = cvtpk_bf16(sb[0],  sb[1]);
        unsigned pb1 = cvtpk_bf16(sb[2],  sb[3]);
        unsigned pb2 = cvtpk_bf16(sb[4],  sb[5]);
        unsigned pb3 = cvtpk_bf16(sb[6],  sb[7]);
        unsigned pb4 = cvtpk_bf16(sb[8],  sb[9]);
        unsigned pb5 = cvtpk_bf16(sb[10], sb[11]);
        unsigned pb6 = cvtpk_bf16(sb[12], sb[13]);
        unsigned pb7 = cvtpk_bf16(sb[14], sb[15]);
        asm("v_permlane32_swap_b32 %0, %1" : "+v"(pa0), "+v"(pa2));
        asm("v_permlane32_swap_b32 %0, %1" : "+v"(pa1), "+v"(pa3));
        asm("v_permlane32_swap_b32 %0, %1" : "+v"(pa4), "+v"(pa6));
        asm("v_permlane32_swap_b32 %0, %1" : "+v"(pa5), "+v"(pa7));
        asm("v_permlane32_swap_b32 %0, %1" : "+v"(pb0), "+v"(pb2));
        asm("v_permlane32_swap_b32 %0, %1" : "+v"(pb1), "+v"(pb3));
        asm("v_permlane32_swap_b32 %0, %1" : "+v"(pb4), "+v"(pb6));
        asm("v_permlane32_swap_b32 %0, %1" : "+v"(pb5), "+v"(pb7));
        union U8 { unsigned u[4]; short8 s; };
        U8 fA0; fA0.u[0] = pa0; fA0.u[1] = pa1; fA0.u[2] = pa2; fA0.u[3] = pa3;
        U8 fA1; fA1.u[0] = pa4; fA1.u[1] = pa5; fA1.u[2] = pa6; fA1.u[3] = pa7;
        U8 fB0; fB0.u[0] = pb0; fB0.u[1] = pb1; fB0.u[2] = pb2; fB0.u[3] = pb3;
        U8 fB1; fB1.u[0] = pb4; fB1.u[1] = pb5; fB1.u[2] = pb6; fB1.u[3] = pb7;

        // O^T += V^T * P^T  (both chains)
        oA0 = __builtin_amdgcn_mfma_f32_32x32x16_bf16(vc0, fA0.s, oA0, 0, 0, 0);
        oB0 = __builtin_amdgcn_mfma_f32_32x32x16_bf16(vc0, fB0.s, oB0, 0, 0, 0);
        oA0 = __builtin_amdgcn_mfma_f32_32x32x16_bf16(vc1, fA1.s, oA0, 0, 0, 0);
        oB0 = __builtin_amdgcn_mfma_f32_32x32x16_bf16(vc1, fB1.s, oB0, 0, 0, 0);
        oA1 = __builtin_amdgcn_mfma_f32_32x32x16_bf16(vc2, fA0.s, oA1, 0, 0, 0);
        oB1 = __builtin_amdgcn_mfma_f32_32x32x16_bf16(vc2, fB0.s, oB1, 0, 0, 0);
        oA1 = __builtin_amdgcn_mfma_f32_32x32x16_bf16(vc3, fA1.s, oA1, 0, 0, 0);
        oB1 = __builtin_amdgcn_mfma_f32_32x32x16_bf16(vc3, fB1.s, oB1, 0, 0, 0);
    }

    // store partials: slotA = (b*544+s)*2, slotB = slotA+1
    int slotA = (b * NTASK2 + s) * 2;
    size_t tbA = ((size_t)slotA * 32 + q32) * 64;
    size_t tbB = ((size_t)(slotA + 1) * 32 + q32) * 64;
#pragma unroll
    for (int hb = 0; hb < 2; hb++) {
#pragma unroll
        for (int g = 0; g < 4; g++) {
            float eA0 = hb ? oA1[4 * g] : oA0[4 * g];
            float eA1 = hb ? oA1[4 * g + 1] : oA0[4 * g + 1];
            float eA2 = hb ? oA1[4 * g + 2] : oA0[4 * g + 2];
            float eA3 = hb ? oA1[4 * g + 3] : oA0[4 * g + 3];
            float eB0 = hb ? oB1[4 * g] : oB0[4 * g];
            float eB1 = hb ? oB1[4 * g + 1] : oB0[4 * g + 1];
            float eB2 = hb ? oB1[4 * g + 2] : oB0[4 * g + 2];
            float eB3 = hb ? oB1[4 * g + 3] : oB0[4 * g + 3];
            int h0 = hb * 32 + g * 8 + hi * 4;
            *reinterpret_cast<uint2*>(Opart + tbA + h0) =
                make_uint2(cvtpk_bf16(eA0, eA1), cvtpk_bf16(eA2, eA3));
            *reinterpret_cast<uint2*>(Opart + tbB + h0) =
                make_uint2(cvtpk_bf16(eB0, eB1), cvtpk_bf16(eB2, eB3));
        }
    }
    if (lane < 32) {
        Mpart[slotA * 32 + q32] = mA;
        Lpart[slotA * 32 + q32] = lA;
        Mpart[(slotA + 1) * 32 + q32] = mB;
        Lpart[(slotA + 1) * 32 + q32] = lB;
    }
}

// ---------------- kernel 3: merge per-chunk partials, divide by l
__global__ __launch_bounds__(256) void attn_merge(const unsigned short* __restrict__ Opart,
                                                  const float* __restrict__ Mpart,
                                                  const float* __restrict__ Lpart,
                                                  float* __restrict__ out) {
    int tid = threadIdx.x;
    int g = blockIdx.x * 64 + (tid >> 2);   // global row
    int h0 = (tid & 3) * 16;
    int b = g >> 12, t = g & 4095;
    int tile32 = t >> 5, r32 = t & 31;
    int st = tile32 >> 1, member = tile32 & 1;
    int k = (st >> 2) + 1;                       // chunks for this supertile
    int sbase = 4 * (136 - ((k * (k + 1)) >> 1));
    int ti = 4 * k - 1 - st;
    int s0 = sbase + ti * k;
    int slot0 = (b * NTASK2 + s0) * 2 + member;  // slots: slot0 + 2*i

    float mm = -3e38f;
    for (int i = 0; i < k; i++) mm = fmaxf(mm, Mpart[(slot0 + 2 * i) * 32 + r32]);
    float ll = 0.f;
    float acc[16];
#pragma unroll
    for (int e = 0; e < 16; e++) acc[e] = 0.f;
    for (int i = 0; i < k; i++) {
        int slot = slot0 + 2 * i;
        float a = exp2f(Mpart[slot * 32 + r32] - mm);
        ll += a * Lpart[slot * 32 + r32];
        const unsigned short* op = Opart + ((size_t)slot * 32 + r32) * 64 + h0;
        short8 v0 = *(const short8*)op;
        short8 v1 = *(const short8*)(op + 8);
#pragma unroll
        for (int e = 0; e < 8; e++) {
            acc[e]     += a * bf16_to_f32((unsigned short)v0[e]);
            acc[8 + e] += a * bf16_to_f32((unsigned short)v1[e]);
        }
    }
    float inv = 1.f / ll;
    float* dst = out + (size_t)g * 64 + h0;
#pragma unroll
    for (int e = 0; e < 16; e++) dst[e] = acc[e] * inv;
}

extern "C" void kernel_launch(void* const* d_in, const int* in_sizes, int n_in,
                              void* d_out, int out_size, void* d_ws, size_t ws_size,
                              hipStream_t stream) {
    (void)in_sizes; (void)n_in; (void)out_size; (void)ws_size;
    const float* x  = (const float*)d_in[0];
    const float* Wk = (const float*)d_in[1];
    const float* Wq = (const float*)d_in[2];
    const float* Wv = (const float*)d_in[3];
    float* out = (float*)d_out;

    unsigned short* Wb = (unsigned short*)d_ws;              // 192*1024 (plain)
    unsigned short* Kb = Wb + 196608;                        // 16384*64
    unsigned short* Qb = Kb + 1048576;                       // pre-scaled by QSCALE
    unsigned short* Vt = Qb + 1048576;                       // (b, 64, t)
    unsigned short* Opart = Vt + 1048576;                    // [4*544*2][32][64] bf16
    float* Mpart = (float*)(Opart + (size_t)4 * NTASK2 * 2 * 32 * 64);
    float* Lpart = Mpart + 4 * NTASK2 * 2 * 32;

    hipLaunchKernelGGL(convert_w, dim3(96), dim3(256), 0, stream, Wk, Wq, Wv, Wb);
    hipLaunchKernelGGL(qkv_proj, dim3(1024), dim3(256), 0, stream, x, Wb, Kb, Qb, Vt);
    hipLaunchKernelGGL(attn, dim3(4 * NTASK2), dim3(64), 0, stream, Qb, Kb, Vt, Opart, Mpart, Lpart);
    hipLaunchKernelGGL(attn_merge, dim3(256), dim3(256), 0, stream, Opart, Mpart, Lpart, out);
}

// Round 14
// 79.040 us; speedup vs baseline: 1.6243x; 1.6243x over previous
//
#include <hip/hip_runtime.h>
#include <hip/hip_bf16.h>

#define D_EMB 1024
#define T_LEN 4096
#define NTASK2 544  // attn supertile-tasks per batch: sum of ceil((st+1)/4), st=0..63

typedef short short8 __attribute__((ext_vector_type(8)));
typedef float f32x4 __attribute__((ext_vector_type(4)));
typedef float f32x16 __attribute__((ext_vector_type(16)));
typedef float float4v __attribute__((ext_vector_type(4)));

__device__ __forceinline__ unsigned short f32_to_bf16(float f) {
    union { float f; unsigned int u; } c; c.f = f;
    unsigned int u = c.u;
    return (unsigned short)((u + 0x7FFFu + ((u >> 16) & 1u)) >> 16);
}
__device__ __forceinline__ float bf16_to_f32(unsigned short v) {
    union { unsigned int u; float f; } c; c.u = ((unsigned int)v) << 16;
    return c.f;
}
__device__ __forceinline__ unsigned cvtpk_bf16(float a, float b) {
    unsigned r;
    asm("v_cvt_pk_bf16_f32 %0, %1, %2" : "=v"(r) : "v"(a), "v"(b));
    return r;
}
// cross-half (lane i <-> i+32) reduce -- known-good __shfl_xor form
__device__ __forceinline__ float xhalf_max(float x) {
    return fmaxf(x, __shfl_xor(x, 32));
}
__device__ __forceinline__ float xhalf_add(float x) {
    return x + __shfl_xor(x, 32);
}
__device__ __forceinline__ void gl_lds16(const void* g, void* l) {
    __builtin_amdgcn_global_load_lds(
        (const __attribute__((address_space(1))) unsigned int*)(g),
        (__attribute__((address_space(3))) unsigned int*)(l), 16, 0, 0);
}

// scale folded into Q: 1/sqrt(64) * log2(e)  (softmax done in exp2 domain)
#define QSCALE (0.125f * 1.44269504f)

// ---------------- kernel 0: convert W -> bf16, XOR-swizzled within 64-col blocks
// (required by the LDS-staged qkv: linear gl_lds dest + swizzled source ==
// swizzled read; rule #21 both-sides-or-neither)
__global__ __launch_bounds__(256) void convert_w(const float* __restrict__ Wk,
                                                 const float* __restrict__ Wq,
                                                 const float* __restrict__ Wv,
                                                 unsigned short* __restrict__ Wb) {
    int e = (blockIdx.x * 256 + threadIdx.x) * 8;
    const float* src;
    if (e < 65536) src = Wk + e;
    else if (e < 131072) src = Wq + (e - 65536);
    else src = Wv + (e - 131072);
    float4v a0 = *(const float4v*)src;
    float4v a1 = *(const float4v*)(src + 4);
    short8 r;
    r[0] = (short)f32_to_bf16(a0[0]); r[1] = (short)f32_to_bf16(a0[1]);
    r[2] = (short)f32_to_bf16(a0[2]); r[3] = (short)f32_to_bf16(a0[3]);
    r[4] = (short)f32_to_bf16(a1[0]); r[5] = (short)f32_to_bf16(a1[1]);
    r[6] = (short)f32_to_bf16(a1[2]); r[7] = (short)f32_to_bf16(a1[3]);
    int row = e >> 10;
    int dst = e ^ ((row & 7) << 3);
    *(short8*)(Wb + dst) = r;
}

// ---------------- kernel 1: QKV projection, LDS-staged GEMM with T4 counted-vmcnt.
// Per BK=64 step: issue x(kt+1) regs + stage(kt+1) into LDS dbuf (8 VMEM ops),
// then sched_barrier; s_waitcnt vmcnt(8) (waits ONLY for the previous step's
// loads); raw s_barrier; sched_barrier; compute step kt. The 8 new loads stay
// in flight across the barrier (guide T4/m198) instead of being drained by
// __syncthreads' vmcnt(0).
__global__ __launch_bounds__(256, 2) void qkv_proj(const float* __restrict__ x,
                                                   const unsigned short* __restrict__ Wb,
                                                   unsigned short* __restrict__ Kb,
                                                   unsigned short* __restrict__ Qb,
                                                   unsigned short* __restrict__ Vt) {
    __shared__ __attribute__((aligned(16))) unsigned short Wsl[2][12288];  // [192][64] bf16

    int tid = threadIdx.x;
    int lane = tid & 63, wave = tid >> 6;
    int lo = lane & 15, hi = lane >> 4;
    int rg = wave >> 1, nh = wave & 1;
    int row0 = blockIdx.x * 32;

    const float* xp = x + (size_t)(row0 + rg * 16 + lo) * D_EMB + hi * 8;

    f32x4 acc[6];
#pragma unroll
    for (int i = 0; i < 6; i++) acc[i] = (f32x4){0.f, 0.f, 0.f, 0.f};

    // prologue: issue x(0) and stage slice 0 (8 VMEM ops in flight)
    float4v xa0 = *(const float4v*)(xp);
    float4v xa1 = *(const float4v*)(xp + 4);
    float4v xa2 = *(const float4v*)(xp + 32);
    float4v xa3 = *(const float4v*)(xp + 36);
#pragma unroll
    for (int j = 0; j < 6; j++) {
        int unit = j * 4 + wave;
        int u = unit * 64 + lane;
        gl_lds16(Wb + (size_t)(u >> 3) * D_EMB + (u & 7) * 8, &Wsl[0][unit * 512]);
    }

    int buf = 0;
    int xorm = (lo & 7) << 4;
    int rowbase = nh * 96 + lo;

    for (int kt = 0; kt < 16; kt++) {
        float4v xn0, xn1, xn2, xn3;
        if (kt < 15) {
            // issue x(kt+1) + stage(kt+1): the 8 newest VMEM ops
            const float* pn = xp + (kt + 1) * 64;
            xn0 = *(const float4v*)(pn);
            xn1 = *(const float4v*)(pn + 4);
            xn2 = *(const float4v*)(pn + 32);
            xn3 = *(const float4v*)(pn + 36);
            int k0n = (kt + 1) * 64;
#pragma unroll
            for (int j = 0; j < 6; j++) {
                int unit = j * 4 + wave;
                int u = unit * 64 + lane;
                gl_lds16(Wb + (size_t)(u >> 3) * D_EMB + k0n + (u & 7) * 8,
                         &Wsl[buf ^ 1][unit * 512]);
            }
        }
        __builtin_amdgcn_sched_barrier(0);
        if (kt < 15) {
            asm volatile("s_waitcnt vmcnt(8)" ::: "memory");  // prev step's 8 done
        } else {
            asm volatile("s_waitcnt vmcnt(0)" ::: "memory");  // final drain
        }
        __builtin_amdgcn_s_barrier();
        __builtin_amdgcn_sched_barrier(0);

        // compute step kt from buf (x regs loaded last step, now complete)
        short8 af[2];
        {
            union { unsigned u[4]; short8 s; } c;
            c.u[0] = cvtpk_bf16(xa0[0], xa0[1]);
            c.u[1] = cvtpk_bf16(xa0[2], xa0[3]);
            c.u[2] = cvtpk_bf16(xa1[0], xa1[1]);
            c.u[3] = cvtpk_bf16(xa1[2], xa1[3]);
            af[0] = c.s;
            c.u[0] = cvtpk_bf16(xa2[0], xa2[1]);
            c.u[1] = cvtpk_bf16(xa2[2], xa2[3]);
            c.u[2] = cvtpk_bf16(xa3[0], xa3[1]);
            c.u[3] = cvtpk_bf16(xa3[2], xa3[3]);
            af[1] = c.s;
        }
        const char* sb = (const char*)&Wsl[buf][0];
#pragma unroll
        for (int i = 0; i < 6; i++) {
            int row = rowbase + i * 16;
#pragma unroll
            for (int ks = 0; ks < 2; ks++) {
                short8 bfrag = *(const short8*)(sb + row * 128 + ((ks * 64 + hi * 16) ^ xorm));
                acc[i] = __builtin_amdgcn_mfma_f32_16x16x32_bf16(af[ks], bfrag, acc[i], 0, 0, 0);
            }
        }
        buf ^= 1;
        if (kt < 15) { xa0 = xn0; xa1 = xn1; xa2 = xn2; xa3 = xn3; }
    }

    // epilogue
#pragma unroll
    for (int i = 0; i < 6; i++) {
        int n = nh * 6 + i;
#pragma unroll
        for (int r = 0; r < 4; r++) {
            int grow = row0 + rg * 16 + hi * 4 + r;
            float val = acc[i][r];
            if (n < 4) {
                Kb[(size_t)grow * 64 + n * 16 + lo] = f32_to_bf16(val);
            } else if (n < 8) {
                Qb[(size_t)grow * 64 + (n - 4) * 16 + lo] = f32_to_bf16(val * QSCALE);
            } else {
                int bb = grow >> 12;
                Vt[((size_t)bb * 64 + (n - 8) * 16 + lo) * T_LEN + (grow & 4095)] = f32_to_bf16(val);
            }
        }
    }
}

// ---------------- kernel 2: causal flash attention, 1 wave per supertile-task.
// Dual-chain (two 32-row q-tiles per wave) for intra-wave ILP. (64,3) so the
// full 8.5-waves/CU grid is co-resident ((64,2) capped at 8).
__global__ __launch_bounds__(64, 3) void attn(const unsigned short* __restrict__ Qb,
                                              const unsigned short* __restrict__ Kb,
                                              const unsigned short* __restrict__ Vt,
                                              unsigned short* __restrict__ Opart,
                                              float* __restrict__ Mpart,
                                              float* __restrict__ Lpart) {
    int lane = threadIdx.x;
    int q32 = lane & 31;
    int hi = lane >> 5;
    unsigned lin = blockIdx.x;
    int b = lin & 3;
    int s = (int)(((lin >> 3) << 1) | ((lin >> 2) & 1));  // 0..543, heavy first

    // decode (supertile st, chunk c): group k has 4 supertiles, k chunks each
    int k = 16, rem = s;
    while (rem >= 4 * k) { rem -= 4 * k; k--; }
    int ti = rem / k;
    int st = 4 * k - 1 - ti;
    int c = rem - ti * k;

    int u0 = c * 8;
    int u1 = min(u0 + 8, 2 * st + 2);   // 32-key units
    int ta = 2 * st, tb = ta + 1;       // the two 32-row tiles
    int qrowA = 64 * st + q32;
    int qrowB = qrowA + 32;

    size_t base = (size_t)b * T_LEN;

    // Q B-fragments for both tiles
    short8 qfa[4], qfb[4];
    const unsigned short* qpa = Qb + (base + qrowA) * 64 + hi * 8;
    const unsigned short* qpb = Qb + (base + qrowB) * 64 + hi * 8;
#pragma unroll
    for (int d = 0; d < 4; d++) {
        qfa[d] = *(const short8*)(qpa + d * 16);
        qfb[d] = *(const short8*)(qpb + d * 16);
    }

    size_t vbase = ((size_t)b * 64 + q32) * T_LEN;
    f32x16 oA0 = {0.f}, oA1 = {0.f}, oB0 = {0.f}, oB1 = {0.f};
    float mA = -3e38f, lA = 0.f, mB = -3e38f, lB = 0.f;

    for (int u = u0; u < u1; ++u) {
        const unsigned short* kp = Kb + (base + u * 32 + q32) * 64 + hi * 8;
        short8 kc0 = *(const short8*)kp;
        short8 kc1 = *(const short8*)(kp + 16);
        short8 kc2 = *(const short8*)(kp + 32);
        short8 kc3 = *(const short8*)(kp + 48);
        const unsigned short* vp = Vt + vbase + u * 32 + hi * 8;
        short8 vc0 = *(const short8*)vp;
        short8 vc1 = *(const short8*)(vp + 16);
        short8 vc2 = *(const short8*)(vp + 32 * T_LEN);
        short8 vc3 = *(const short8*)(vp + 32 * T_LEN + 16);

        // S^T = K * Q^T for both tiles (independent MFMA chains)
        f32x16 sa = {0.f}, sb = {0.f};
        sa = __builtin_amdgcn_mfma_f32_32x32x16_bf16(kc0, qfa[0], sa, 0, 0, 0);
        sb = __builtin_amdgcn_mfma_f32_32x32x16_bf16(kc0, qfb[0], sb, 0, 0, 0);
        sa = __builtin_amdgcn_mfma_f32_32x32x16_bf16(kc1, qfa[1], sa, 0, 0, 0);
        sb = __builtin_amdgcn_mfma_f32_32x32x16_bf16(kc1, qfb[1], sb, 0, 0, 0);
        sa = __builtin_amdgcn_mfma_f32_32x32x16_bf16(kc2, qfa[2], sa, 0, 0, 0);
        sb = __builtin_amdgcn_mfma_f32_32x32x16_bf16(kc2, qfb[2], sb, 0, 0, 0);
        sa = __builtin_amdgcn_mfma_f32_32x32x16_bf16(kc3, qfa[3], sa, 0, 0, 0);
        sb = __builtin_amdgcn_mfma_f32_32x32x16_bf16(kc3, qfb[3], sb, 0, 0, 0);

        // causal mask: chain A when u >= ta (u==tb -> fully masked, harmless);
        // chain B only at u == tb
        if (u >= ta) {
#pragma unroll
            for (int r = 0; r < 16; ++r) {
                int key = 32 * u + (r & 3) + 8 * (r >> 2) + 4 * hi;
                sa[r] = (key <= qrowA) ? sa[r] : -3e38f;
                if (u == tb) sb[r] = (key <= qrowB) ? sb[r] : -3e38f;
            }
        }

        // row max (both chains) + cross-half
        float a0 = fmaxf(fmaxf(sa[0], sa[1]), sa[2]);
        float a1 = fmaxf(fmaxf(sa[3], sa[4]), sa[5]);
        float a2 = fmaxf(fmaxf(sa[6], sa[7]), sa[8]);
        float a3 = fmaxf(fmaxf(sa[9], sa[10]), sa[11]);
        float a4 = fmaxf(fmaxf(sa[12], sa[13]), sa[14]);
        float mxA = fmaxf(fmaxf(fmaxf(a0, a1), fmaxf(a2, a3)), fmaxf(a4, sa[15]));
        float b0 = fmaxf(fmaxf(sb[0], sb[1]), sb[2]);
        float b1 = fmaxf(fmaxf(sb[3], sb[4]), sb[5]);
        float b2 = fmaxf(fmaxf(sb[6], sb[7]), sb[8]);
        float b3 = fmaxf(fmaxf(sb[9], sb[10]), sb[11]);
        float b4 = fmaxf(fmaxf(sb[12], sb[13]), sb[14]);
        float mxB = fmaxf(fmaxf(fmaxf(b0, b1), fmaxf(b2, b3)), fmaxf(b4, sb[15]));
        mxA = xhalf_max(mxA);
        mxB = xhalf_max(mxB);

        // combined defer-max (THR=8): neutral rescale is exact for the
        // chain that didn't grow (al = exp2(0) = 1)
        float grow = fmaxf(mxA - mA, mxB - mB);
        if (__any(grow > 8.0f)) {
            float mnA = fmaxf(mA, mxA);
            float alA = exp2f(mA - mnA);
            mA = mnA; lA *= alA;
            float mnB = fmaxf(mB, mxB);
            float alB = exp2f(mB - mnB);
            mB = mnB; lB *= alB;
#pragma unroll
            for (int r = 0; r < 16; ++r) {
                oA0[r] *= alA; oA1[r] *= alA;
                oB0[r] *= alB; oB1[r] *= alB;
            }
        }

#pragma unroll
        for (int r = 0; r < 16; ++r) {
            sa[r] = exp2f(sa[r] - mA);
            sb[r] = exp2f(sb[r] - mB);
        }
        float yA = ((sa[0] + sa[8]) + (sa[4] + sa[12])) + ((sa[1] + sa[9]) + (sa[5] + sa[13]))
                 + ((sa[2] + sa[10]) + (sa[6] + sa[14])) + ((sa[3] + sa[11]) + (sa[7] + sa[15]));
        float yB = ((sb[0] + sb[8]) + (sb[4] + sb[12])) + ((sb[1] + sb[9]) + (sb[5] + sb[13]))
                 + ((sb[2] + sb[10]) + (sb[6] + sb[14])) + ((sb[3] + sb[11]) + (sb[7] + sb[15]));
        lA += xhalf_add(yA);
        lB += xhalf_add(yB);

        // pack P -> bf16 PV B-fragments (cvt_pk + permlane32_swap), both chains
        unsigned pa0 = cvtpk_bf16(sa[0],  sa[1]);
        unsigned pa1 = cvtpk_bf16(sa[2],  sa[3]);
        unsigned pa2 = cvtpk_bf16(sa[4],  sa[5]);
        unsigned pa3 = cvtpk_bf16(sa[6],  sa[7]);
        unsigned pa4 = cvtpk_bf16(sa[8],  sa[9]);
        unsigned pa5 = cvtpk_bf16(sa[10], sa[11]);
        unsigned pa6 = cvtpk_bf16(sa[12], sa[13]);
        unsigned pa7 = cvtpk_bf16(sa[14], sa[15]);
        unsigned pb0 = cvtpk_bf16(sb[0],  sb[1]);
        unsigned pb1 = cvtpk_bf16(sb[2],  sb[3]);
        unsigned pb2 = cvtpk_bf16(sb[4],  sb[5]);
        unsigned pb3 = cvtpk_bf16(sb[6],  sb[7]);
        unsigned pb4 = cvtpk_bf16(sb[8],  sb[9]);
        unsigned pb5 = cvtpk_bf16(sb[10], sb[11]);
        unsigned pb6 = cvtpk_bf16(sb[12], sb[13]);
        unsigned pb7 = cvtpk_bf16(sb[14], sb[15]);
        asm("v_permlane32_swap_b32 %0, %1" : "+v"(pa0), "+v"(pa2));
        asm("v_permlane32_swap_b32 %0, %1" : "+v"(pa1), "+v"(pa3));
        asm("v_permlane32_swap_b32 %0, %1" : "+v"(pa4), "+v"(pa6));
        asm("v_permlane32_swap_b32 %0, %1" : "+v"(pa5), "+v"(pa7));
        asm("v_permlane32_swap_b32 %0, %1" : "+v"(pb0), "+v"(pb2));
        asm("v_permlane32_swap_b32 %0, %1" : "+v"(pb1), "+v"(pb3));
        asm("v_permlane32_swap_b32 %0, %1" : "+v"(pb4), "+v"(pb6));
        asm("v_permlane32_swap_b32 %0, %1" : "+v"(pb5), "+v"(pb7));
        union U8 { unsigned u[4]; short8 s; };
        U8 fA0; fA0.u[0] = pa0; fA0.u[1] = pa1; fA0.u[2] = pa2; fA0.u[3] = pa3;
        U8 fA1; fA1.u[0] = pa4; fA1.u[1] = pa5; fA1.u[2] = pa6; fA1.u[3] = pa7;
        U8 fB0; fB0.u[0] = pb0; fB0.u[1] = pb1; fB0.u[2] = pb2; fB0.u[3] = pb3;
        U8 fB1; fB1.u[0] = pb4; fB1.u[1] = pb5; fB1.u[2] = pb6; fB1.u[3] = pb7;

        // O^T += V^T * P^T  (both chains)
        oA0 = __builtin_amdgcn_mfma_f32_32x32x16_bf16(vc0, fA0.s, oA0, 0, 0, 0);
        oB0 = __builtin_amdgcn_mfma_f32_32x32x16_bf16(vc0, fB0.s, oB0, 0, 0, 0);
        oA0 = __builtin_amdgcn_mfma_f32_32x32x16_bf16(vc1, fA1.s, oA0, 0, 0, 0);
        oB0 = __builtin_amdgcn_mfma_f32_32x32x16_bf16(vc1, fB1.s, oB0, 0, 0, 0);
        oA1 = __builtin_amdgcn_mfma_f32_32x32x16_bf16(vc2, fA0.s, oA1, 0, 0, 0);
        oB1 = __builtin_amdgcn_mfma_f32_32x32x16_bf16(vc2, fB0.s, oB1, 0, 0, 0);
        oA1 = __builtin_amdgcn_mfma_f32_32x32x16_bf16(vc3, fA1.s, oA1, 0, 0, 0);
        oB1 = __builtin_amdgcn_mfma_f32_32x32x16_bf16(vc3, fB1.s, oB1, 0, 0, 0);
    }

    // store partials: slotA = (b*544+s)*2, slotB = slotA+1
    int slotA = (b * NTASK2 + s) * 2;
    size_t tbA = ((size_t)slotA * 32 + q32) * 64;
    size_t tbB = ((size_t)(slotA + 1) * 32 + q32) * 64;
#pragma unroll
    for (int hb = 0; hb < 2; hb++) {
#pragma unroll
        for (int g = 0; g < 4; g++) {
            float eA0 = hb ? oA1[4 * g] : oA0[4 * g];
            float eA1 = hb ? oA1[4 * g + 1] : oA0[4 * g + 1];
            float eA2 = hb ? oA1[4 * g + 2] : oA0[4 * g + 2];
            float eA3 = hb ? oA1[4 * g + 3] : oA0[4 * g + 3];
            float eB0 = hb ? oB1[4 * g] : oB0[4 * g];
            float eB1 = hb ? oB1[4 * g + 1] : oB0[4 * g + 1];
            float eB2 = hb ? oB1[4 * g + 2] : oB0[4 * g + 2];
            float eB3 = hb ? oB1[4 * g + 3] : oB0[4 * g + 3];
            int h0 = hb * 32 + g * 8 + hi * 4;
            *reinterpret_cast<uint2*>(Opart + tbA + h0) =
                make_uint2(cvtpk_bf16(eA0, eA1), cvtpk_bf16(eA2, eA3));
            *reinterpret_cast<uint2*>(Opart + tbB + h0) =
                make_uint2(cvtpk_bf16(eB0, eB1), cvtpk_bf16(eB2, eB3));
        }
    }
    if (lane < 32) {
        Mpart[slotA * 32 + q32] = mA;
        Lpart[slotA * 32 + q32] = lA;
        Mpart[(slotA + 1) * 32 + q32] = mB;
        Lpart[(slotA + 1) * 32 + q32] = lB;
    }
}

// ---------------- kernel 3: merge per-chunk partials, divide by l
__global__ __launch_bounds__(256) void attn_merge(const unsigned short* __restrict__ Opart,
                                                  const float* __restrict__ Mpart,
                                                  const float* __restrict__ Lpart,
                                                  float* __restrict__ out) {
    int tid = threadIdx.x;
    int g = blockIdx.x * 64 + (tid >> 2);   // global row
    int h0 = (tid & 3) * 16;
    int b = g >> 12, t = g & 4095;
    int tile32 = t >> 5, r32 = t & 31;
    int st = tile32 >> 1, member = tile32 & 1;
    int k = (st >> 2) + 1;                       // chunks for this supertile
    int sbase = 4 * (136 - ((k * (k + 1)) >> 1));
    int ti = 4 * k - 1 - st;
    int s0 = sbase + ti * k;
    int slot0 = (b * NTASK2 + s0) * 2 + member;  // slots: slot0 + 2*i

    float mm = -3e38f;
    for (int i = 0; i < k; i++) mm = fmaxf(mm, Mpart[(slot0 + 2 * i) * 32 + r32]);
    float ll = 0.f;
    float acc[16];
#pragma unroll
    for (int e = 0; e < 16; e++) acc[e] = 0.f;
    for (int i = 0; i < k; i++) {
        int slot = slot0 + 2 * i;
        float a = exp2f(Mpart[slot * 32 + r32] - mm);
        ll += a * Lpart[slot * 32 + r32];
        const unsigned short* op = Opart + ((size_t)slot * 32 + r32) * 64 + h0;
        short8 v0 = *(const short8*)op;
        short8 v1 = *(const short8*)(op + 8);
#pragma unroll
        for (int e = 0; e < 8; e++) {
            acc[e]     += a * bf16_to_f32((unsigned short)v0[e]);
            acc[8 + e] += a * bf16_to_f32((unsigned short)v1[e]);
        }
    }
    float inv = 1.f / ll;
    float* dst = out + (size_t)g * 64 + h0;
#pragma unroll
    for (int e = 0; e < 16; e++) dst[e] = acc[e] * inv;
}

extern "C" void kernel_launch(void* const* d_in, const int* in_sizes, int n_in,
                              void* d_out, int out_size, void* d_ws, size_t ws_size,
                              hipStream_t stream) {
    (void)in_sizes; (void)n_in; (void)out_size; (void)ws_size;
    const float* x  = (const float*)d_in[0];
    const float* Wk = (const float*)d_in[1];
    const float* Wq = (const float*)d_in[2];
    const float* Wv = (const float*)d_in[3];
    float* out = (float*)d_out;

    unsigned short* Wb = (unsigned short*)d_ws;              // 192*1024 (swizzled)
    unsigned short* Kb = Wb + 196608;                        // 16384*64
    unsigned short* Qb = Kb + 1048576;                       // pre-scaled by QSCALE
    unsigned short* Vt = Qb + 1048576;                       // (b, 64, t)
    unsigned short* Opart = Vt + 1048576;                    // [4*544*2][32][64] bf16
    float* Mpart = (float*)(Opart + (size_t)4 * NTASK2 * 2 * 32 * 64);
    float* Lpart = Mpart + 4 * NTASK2 * 2 * 32;

    hipLaunchKernelGGL(convert_w, dim3(96), dim3(256), 0, stream, Wk, Wq, Wv, Wb);
    hipLaunchKernelGGL(qkv_proj, dim3(512), dim3(256), 0, stream, x, Wb, Kb, Qb, Vt);
    hipLaunchKernelGGL(attn, dim3(4 * NTASK2), dim3(64), 0, stream, Qb, Kb, Vt, Opart, Mpart, Lpart);
    hipLaunchKernelGGL(attn_merge, dim3(256), dim3(256), 0, stream, Opart, Mpart, Lpart, out);
}